// Round 6
// baseline (478.253 us; speedup 1.0000x reference)
//
#include <hip/hip_runtime.h>
#include <hip/hip_bf16.h>

typedef __attribute__((ext_vector_type(8))) short short8;
typedef __attribute__((ext_vector_type(4))) float f32x4;
typedef unsigned short u16;
typedef unsigned int u32;

#define NROWS 16384
#define KDIM 16384
#define EPS 1e-6f

__device__ __forceinline__ u16 f2bf(float x) {
    union { float f; u32 u; } v; v.f = x;
    u32 u = v.u;
    u32 r = (u + 0x7FFFu + ((u >> 16) & 1u)) >> 16;  // RNE
    return (u16)r;
}

__device__ __forceinline__ short cvbf(float x) {
    __hip_bfloat16 h = __float2bfloat16(x);
    return *(short*)&h;
}

__device__ __forceinline__ short8 cvt8(float4 a, float4 b) {
    short8 r = { cvbf(a.x), cvbf(a.y), cvbf(a.z), cvbf(a.w),
                 cvbf(b.x), cvbf(b.y), cvbf(b.z), cvbf(b.w) };
    return r;
}

// ---------------- Stage 0: transpose weight -> Wt[64][256] ----------------
__global__ __launch_bounds__(256) void wt_kernel(const float* __restrict__ W,
                                                 float* __restrict__ Wt) {
    int idx = blockIdx.x * 256 + threadIdx.x;  // 16384
    int k = idx >> 6, c = idx & 63;
    Wt[c * 256 + k] = W[idx];
}

// ---------------- Stage 1: support = input @ W (fp32) ---------------------
__global__ __launch_bounds__(256) void support_kernel(
    const float* __restrict__ inp, const float* __restrict__ Wt,
    float* __restrict__ sup)
{
    int tid = threadIdx.x;
    int col = tid & 63;
    int rr = tid >> 6;                        // 0..3
    int rowbase = blockIdx.x * 32 + rr * 8;   // 8 rows per thread
    const float4* wt4 = (const float4*)(Wt + (size_t)col * 256);
    float acc[8];
#pragma unroll
    for (int i = 0; i < 8; ++i) acc[i] = 0.f;
    for (int k4 = 0; k4 < 64; ++k4) {
        float4 wv = wt4[k4];
#pragma unroll
        for (int i = 0; i < 8; ++i) {
            float4 iv = *((const float4*)(inp + (size_t)(rowbase + i) * 256) + k4);
            acc[i] += iv.x * wv.x + iv.y * wv.y + iv.z * wv.z + iv.w * wv.w;
        }
    }
#pragma unroll
    for (int i = 0; i < 8; ++i)
        sup[(size_t)(rowbase + i) * 64 + col] = acc[i];
}

// ---------------- Stage 2: global min ------------------------------------
__global__ __launch_bounds__(256) void min_part_kernel(
    const float* __restrict__ sup, float* __restrict__ partmin)
{
    __shared__ float wmin[4];
    int tid = threadIdx.x;
    const float4* s4 = (const float4*)sup;
    size_t idx = (size_t)blockIdx.x * 256 + tid;
    float m = 3.4e38f;
#pragma unroll
    for (int j = 0; j < 4; ++j) {
        float4 v = s4[idx + (size_t)j * 65536];
        m = fminf(m, fminf(fminf(v.x, v.y), fminf(v.z, v.w)));
    }
#pragma unroll
    for (int off = 32; off; off >>= 1) m = fminf(m, __shfl_down(m, off, 64));
    if ((tid & 63) == 0) wmin[tid >> 6] = m;
    __syncthreads();
    if (tid == 0)
        partmin[blockIdx.x] = fminf(fminf(wmin[0], wmin[1]), fminf(wmin[2], wmin[3]));
}

__global__ __launch_bounds__(256) void min_final_kernel(
    const float* __restrict__ partmin, float* __restrict__ mu)
{
    __shared__ float wmin[4];
    int tid = threadIdx.x;
    float m = partmin[tid];
#pragma unroll
    for (int off = 32; off; off >>= 1) m = fminf(m, __shfl_down(m, off, 64));
    if ((tid & 63) == 0) wmin[tid >> 6] = m;
    __syncthreads();
    if (tid == 0)
        mu[0] = fminf(fminf(wmin[0], wmin[1]), fminf(wmin[2], wmin[3]));
}

// ---------------- Stage 3: Bt[n][k] bf16; n<64: s^(p+1), n>=64: s^p -------
__global__ __launch_bounds__(256) void build_bt_kernel(
    const float* __restrict__ sup, const float* __restrict__ muptr,
    const int* __restrict__ pptr, u16* __restrict__ Bt)
{
    int k = blockIdx.x * 256 + threadIdx.x;   // 0..16383
    float mu = *muptr;
    int p = *pptr;
    const float4* srow = (const float4*)(sup + (size_t)k * 64);
#pragma unroll
    for (int j = 0; j < 16; ++j) {
        float4 v = srow[j];
        float ss[4] = {v.x, v.y, v.z, v.w};
#pragma unroll
        for (int q = 0; q < 4; ++q) {
            int c = j * 4 + q;
            float s = ss[q] - mu + EPS;
            float d = 1.f;
            for (int i = 0; i < p; ++i) d *= s;   // s^p
            Bt[(size_t)c * KDIM + k] = f2bf(d * s);          // top
            Bt[(size_t)(c + 64) * KDIM + k] = f2bf(d);       // down
        }
    }
}

// ---------------- Stage 4: barrier-free streaming GEMM, K-split=4 ---------
// No LDS, no __syncthreads. Each wave owns 32 rows x 128 cols and streams
// its K-quarter, loading MFMA fragments DIRECTLY from global:
//   A-frag: lane = (row=l15 [+16], k=lg*8+j)  -> 2x dwordx4 f32 + cvt
//   B-frag: lane = (col=l15,      k=lg*8+j)  -> 1x dwordx4 bf16
// (identical register layouts to the LDS-fed fragments of rounds 1-5).
// Block = 4 waves = 128 rows. Grid 512 = 2 blocks/CU, 8 waves/CU.
// XCD remap: each XCD serves one K-quarter -> 1MB Bt slice L2-resident.
#define KSPLIT 4
#define KR (KDIM / KSPLIT)   // 4096
#define GITERS (KR / 32)     // 128

__global__ __launch_bounds__(256, 2) void gemm_kernel(
    const float* __restrict__ adj, const u16* __restrict__ Bt,
    float* __restrict__ Pp)
{
    const int tid  = threadIdx.x;
    const int lane = tid & 63;
    const int w    = tid >> 6;          // 0..3
    const int l15  = lane & 15;
    const int lg   = lane >> 4;         // 0..3

    // bijective remap: P -> (kq, rowgroup); XCD = P%8 serves kq = XCD>>1
    const int P    = blockIdx.x;        // 0..511
    const int xcd  = P & 7;
    const int slot = P >> 3;            // 0..63
    const int kq   = xcd >> 1;          // 0..3
    const int rg   = slot * 2 + (xcd & 1);   // 0..127

    const size_t rowbase = (size_t)rg * 128 + w * 32;
    const size_t kbase   = (size_t)kq * KR;

    const float* a0p = adj + (rowbase + l15) * KDIM + kbase + lg * 8;
    const float* a1p = a0p + (size_t)16 * KDIM;
    const u16*   bbp = Bt + (size_t)l15 * KDIM + kbase + lg * 8;

    f32x4 acc0[8], acc1[8];
#pragma unroll
    for (int cf = 0; cf < 8; ++cf) {
        acc0[cf] = (f32x4){0.f, 0.f, 0.f, 0.f};
        acc1[cf] = acc0[cf];
    }

#pragma unroll 2
    for (int it = 0; it < GITERS; ++it) {
        const int ko = it * 32;
        // A fragments (f32 -> bf16)
        const float4* A0 = (const float4*)(a0p + ko);
        const float4* A1 = (const float4*)(a1p + ko);
        float4 fa0 = A0[0], fa1 = A0[1];
        float4 fb0 = A1[0], fb1 = A1[1];
        // B fragments (bf16 direct)
        short8 b[8];
#pragma unroll
        for (int cf = 0; cf < 8; ++cf)
            b[cf] = *(const short8*)(bbp + (size_t)(cf * 16) * KDIM + ko);
        short8 a0 = cvt8(fa0, fa1);
        short8 a1 = cvt8(fb0, fb1);
#pragma unroll
        for (int cf = 0; cf < 8; ++cf) {
            acc0[cf] = __builtin_amdgcn_mfma_f32_16x16x32_bf16(a0, b[cf], acc0[cf], 0, 0, 0);
            acc1[cf] = __builtin_amdgcn_mfma_f32_16x16x32_bf16(a1, b[cf], acc1[cf], 0, 0, 0);
        }
    }

    // store partials: Pp[kq][row 0..16383][col 0..127]
    // C layout: col = l15 (+cf*16), row = lg*4 + q (+16 for acc1)
    float* pb = Pp + ((size_t)kq * NROWS + rowbase) * 128;
#pragma unroll
    for (int cf = 0; cf < 8; ++cf) {
#pragma unroll
        for (int q = 0; q < 4; ++q) {
            int r0 = lg * 4 + q;
            int c  = cf * 16 + l15;
            pb[(r0     ) * 128 + c] = acc0[cf][q];
            pb[(r0 + 16) * 128 + c] = acc1[cf][q];
        }
    }
}

// ---------------- Stage 5: combine K-quarters, ratio + mu + bias ----------
__global__ __launch_bounds__(256) void reduce_kernel(
    const float* __restrict__ Pp, const float* __restrict__ bias,
    const float* __restrict__ muptr, float* __restrict__ out)
{
    int idx = blockIdx.x * 256 + threadIdx.x;   // 1M outputs
    int r = idx >> 6, c = idx & 63;
    const float* p = Pp + (size_t)r * 128 + c;
    const size_t qs = (size_t)NROWS * 128;
    float T = 0.f, D = 0.f;
#pragma unroll
    for (int kq = 0; kq < KSPLIT; ++kq) {
        T += p[kq * qs];
        D += p[kq * qs + 64];
    }
    out[idx] = T / D + muptr[0] + bias[c];
}

extern "C" void kernel_launch(void* const* d_in, const int* in_sizes, int n_in,
                              void* d_out, int out_size, void* d_ws, size_t ws_size,
                              hipStream_t stream)
{
    const float* inp  = (const float*)d_in[0];
    const float* adj  = (const float*)d_in[1];
    const float* W    = (const float*)d_in[2];
    const float* bias = (const float*)d_in[3];
    const int*   p    = (const int*)d_in[4];
    float* out = (float*)d_out;

    // ws layout: Bt 4MB | partmin 1KB | mu | Wt 64KB | (8MB:) Pp 32MB
    char* ws = (char*)d_ws;
    u16*   Bt      = (u16*)ws;
    float* partmin = (float*)(ws + (size_t)4 * 1024 * 1024);
    float* mu      = partmin + 256;
    float* Wt      = (float*)(ws + (size_t)4 * 1024 * 1024 + 4096);
    float* Pp      = (float*)(ws + (size_t)8 * 1024 * 1024);

    float* sup = out;   // park support in d_out; reduce overwrites at the end

    wt_kernel       <<<64,   256, 0, stream>>>(W, Wt);
    support_kernel  <<<512,  256, 0, stream>>>(inp, Wt, sup);
    min_part_kernel <<<256,  256, 0, stream>>>(sup, partmin);
    min_final_kernel<<<1,    256, 0, stream>>>(partmin, mu);
    build_bt_kernel <<<64,   256, 0, stream>>>(sup, mu, p, Bt);
    gemm_kernel     <<<512,  256, 0, stream>>>(adj, Bt, Pp);
    reduce_kernel   <<<4096, 256, 0, stream>>>(Pp, bias, mu, out);
}

// Round 7
// 448.280 us; speedup vs baseline: 1.0669x; 1.0669x over previous
//
#include <hip/hip_runtime.h>
#include <hip/hip_bf16.h>

typedef __attribute__((ext_vector_type(8))) short short8;
typedef __attribute__((ext_vector_type(4))) float f32x4;
typedef unsigned short u16;
typedef unsigned int u32;

#define NROWS 16384
#define KDIM 16384
#define EPS 1e-6f

__device__ __forceinline__ u16 f2bf(float x) {
    union { float f; u32 u; } v; v.f = x;
    u32 u = v.u;
    u32 r = (u + 0x7FFFu + ((u >> 16) & 1u)) >> 16;  // RNE
    return (u16)r;
}

__device__ __forceinline__ void glds16(const void* g, void* l) {
    __builtin_amdgcn_global_load_lds(
        (const __attribute__((address_space(1))) void*)g,
        (__attribute__((address_space(3))) void*)l, 16, 0, 0);
}

__device__ __forceinline__ short cvbf(float x) {
    __hip_bfloat16 h = __float2bfloat16(x);
    return *(short*)&h;
}

__device__ __forceinline__ short8 cvt8(float4 a, float4 b) {
    short8 r = { cvbf(a.x), cvbf(a.y), cvbf(a.z), cvbf(a.w),
                 cvbf(b.x), cvbf(b.y), cvbf(b.z), cvbf(b.w) };
    return r;
}

// ---------------- Stage 0: transpose weight -> Wt[64][256] ----------------
__global__ __launch_bounds__(256) void wt_kernel(const float* __restrict__ W,
                                                 float* __restrict__ Wt) {
    int idx = blockIdx.x * 256 + threadIdx.x;  // 16384
    int k = idx >> 6, c = idx & 63;
    Wt[c * 256 + k] = W[idx];
}

// ---------------- Stage 1: support = input @ W (fp32) ---------------------
__global__ __launch_bounds__(256) void support_kernel(
    const float* __restrict__ inp, const float* __restrict__ Wt,
    float* __restrict__ sup)
{
    int tid = threadIdx.x;
    int col = tid & 63;
    int rr = tid >> 6;                        // 0..3
    int rowbase = blockIdx.x * 32 + rr * 8;   // 8 rows per thread
    const float4* wt4 = (const float4*)(Wt + (size_t)col * 256);
    float acc[8];
#pragma unroll
    for (int i = 0; i < 8; ++i) acc[i] = 0.f;
    for (int k4 = 0; k4 < 64; ++k4) {
        float4 wv = wt4[k4];
#pragma unroll
        for (int i = 0; i < 8; ++i) {
            float4 iv = *((const float4*)(inp + (size_t)(rowbase + i) * 256) + k4);
            acc[i] += iv.x * wv.x + iv.y * wv.y + iv.z * wv.z + iv.w * wv.w;
        }
    }
#pragma unroll
    for (int i = 0; i < 8; ++i)
        sup[(size_t)(rowbase + i) * 64 + col] = acc[i];
}

// ---------------- Stage 2: global min ------------------------------------
__global__ __launch_bounds__(256) void min_part_kernel(
    const float* __restrict__ sup, float* __restrict__ partmin)
{
    __shared__ float wmin[4];
    int tid = threadIdx.x;
    const float4* s4 = (const float4*)sup;
    size_t idx = (size_t)blockIdx.x * 256 + tid;
    float m = 3.4e38f;
#pragma unroll
    for (int j = 0; j < 4; ++j) {
        float4 v = s4[idx + (size_t)j * 65536];
        m = fminf(m, fminf(fminf(v.x, v.y), fminf(v.z, v.w)));
    }
#pragma unroll
    for (int off = 32; off; off >>= 1) m = fminf(m, __shfl_down(m, off, 64));
    if ((tid & 63) == 0) wmin[tid >> 6] = m;
    __syncthreads();
    if (tid == 0)
        partmin[blockIdx.x] = fminf(fminf(wmin[0], wmin[1]), fminf(wmin[2], wmin[3]));
}

__global__ __launch_bounds__(256) void min_final_kernel(
    const float* __restrict__ partmin, float* __restrict__ mu)
{
    __shared__ float wmin[4];
    int tid = threadIdx.x;
    float m = partmin[tid];
#pragma unroll
    for (int off = 32; off; off >>= 1) m = fminf(m, __shfl_down(m, off, 64));
    if ((tid & 63) == 0) wmin[tid >> 6] = m;
    __syncthreads();
    if (tid == 0)
        mu[0] = fminf(fminf(wmin[0], wmin[1]), fminf(wmin[2], wmin[3]));
}

// ---------------- Stage 3: Bt[n][k] bf16; n<64: s^(p+1), n>=64: s^p -------
__global__ __launch_bounds__(256) void build_bt_kernel(
    const float* __restrict__ sup, const float* __restrict__ muptr,
    const int* __restrict__ pptr, u16* __restrict__ Bt)
{
    int k = blockIdx.x * 256 + threadIdx.x;   // 0..16383
    float mu = *muptr;
    int p = *pptr;
    const float4* srow = (const float4*)(sup + (size_t)k * 64);
#pragma unroll
    for (int j = 0; j < 16; ++j) {
        float4 v = srow[j];
        float ss[4] = {v.x, v.y, v.z, v.w};
#pragma unroll
        for (int q = 0; q < 4; ++q) {
            int c = j * 4 + q;
            float s = ss[q] - mu + EPS;
            float d = 1.f;
            for (int i = 0; i < p; ++i) d *= s;   // s^p
            Bt[(size_t)c * KDIM + k] = f2bf(d * s);          // top
            Bt[(size_t)(c + 64) * KDIM + k] = f2bf(d);       // down
        }
    }
}

// ---------------- Stage 4: GEMM partials, K-split=2 -----------------------
// LDS-bandwidth-minimal geometry: BM=128, BN=128, BK=64, 256 thr / 4 waves.
// Each wave owns 32 rows x ALL 128 cols (B reused in registers across its
// 2 row-frags; A elements read by exactly ONE wave). Per block-iter LDS =
// 144 KB vs adj-HBM budget ~3120cy -> LDS at ~54% (was ~100% in R2).
// Staging identical to proven R2: glds16 linear dest + inverse-swizzled
// global source; depth-1 double buffer, one __syncthreads per iter.
// Grid 256 = 128 rowgroups x 2 K-halves -> 1 block/CU (96 KB LDS).
// h = blockIdx&1 pins each XCD to one 2MB Bt slice (L2-resident).
#define BM 128
#define BN 128
#define BK 64
#define KH 8192
#define NTI 128   // KH/BK

__global__ __launch_bounds__(256, 1) void gemm_kernel(
    const float* __restrict__ adj, const u16* __restrict__ Bt,
    float* __restrict__ Pp)
{
    __shared__ __align__(16) float Ash[2][BM * BK];   // 32 KB x2 (f32)
    __shared__ __align__(16) u16  Bsh[2][BN * BK];    // 16 KB x2 (bf16)

    const int tid = threadIdx.x;
    const int rg = blockIdx.x >> 1;          // 0..127 rowgroup
    const int h  = blockIdx.x & 1;           // K-half
    const size_t rowbase = (size_t)rg * BM;
    const size_t kbase   = (size_t)h * KH;

    // --- A staging: 2048 granules (16B = 4 floats), 16 granules/row
    const float* asp[8];
#pragma unroll
    for (int j = 0; j < 8; ++j) {
        const int g = tid + j * 256;
        const int ar = g >> 4;                       // 0..127
        const int ax = (g & 15) ^ (ar & 7);          // inverse-swizzled src
        asp[j] = adj + (rowbase + ar) * KDIM + kbase + ax * 4;
    }
    // --- B staging: 1024 granules (16B = 8 bf16), 8 granules/row
    const u16* bsp[4];
#pragma unroll
    for (int j = 0; j < 4; ++j) {
        const int g = tid + j * 256;
        const int bn = g >> 3;                       // 0..127
        const int bx = (g & 7) ^ (bn & 7);
        bsp[j] = Bt + (size_t)bn * KDIM + kbase + bx * 8;
    }

    // --- compute indices: 4 waves, each 32 rows x 128 cols
    const int lane = tid & 63;
    const int w    = tid >> 6;               // 0..3
    const int l15  = lane & 15, lg = lane >> 4;
    const int arow0 = w * 32 + l15;          // row frag 0
    const int arow1 = arow0 + 16;            // row frag 1
    const int asw   = arow0 & 7;             // == arow1 & 7
    const int bswl  = l15 & 7;               // B swizzle (n&7 == l15&7)

    f32x4 acc0[8], acc1[8];
#pragma unroll
    for (int cf = 0; cf < 8; ++cf) {
        acc0[cf] = (f32x4){0.f, 0.f, 0.f, 0.f};
        acc1[cf] = acc0[cf];
    }

    auto stage = [&](int kt, int buf) {
        const int koff = kt * BK;
        char* ab = (char*)Ash[buf];
        char* bb = (char*)Bsh[buf];
#pragma unroll
        for (int j = 0; j < 8; ++j)
            glds16(asp[j] + koff, ab + (tid + j * 256) * 16);
#pragma unroll
        for (int j = 0; j < 4; ++j)
            glds16(bsp[j] + koff, bb + (tid + j * 256) * 16);
    };

    stage(0, 0);

    for (int t = 0; t < NTI; ++t) {
        __syncthreads();                 // tile t resident in buf[t&1]
        if (t + 1 < NTI) stage(t + 1, (t + 1) & 1);
        const float4* As4 = (const float4*)Ash[t & 1];
        const short8* Bs8 = (const short8*)Bsh[t & 1];
#pragma unroll
        for (int ks = 0; ks < 2; ++ks) {
            const int x0 = ks * 8 + lg * 2;
            float4 fa0 = As4[arow0 * 16 + ((x0    ) ^ asw)];
            float4 fa1 = As4[arow0 * 16 + ((x0 + 1) ^ asw)];
            float4 fb0 = As4[arow1 * 16 + ((x0    ) ^ asw)];
            float4 fb1 = As4[arow1 * 16 + ((x0 + 1) ^ asw)];
            short8 a0 = cvt8(fa0, fa1);
            short8 a1 = cvt8(fb0, fb1);
            const int bx = ks * 4 + lg;
#pragma unroll
            for (int cf = 0; cf < 8; ++cf) {
                const int n = cf * 16 + l15;
                short8 b = Bs8[n * 8 + (bx ^ bswl)];
                acc0[cf] = __builtin_amdgcn_mfma_f32_16x16x32_bf16(a0, b, acc0[cf], 0, 0, 0);
                acc1[cf] = __builtin_amdgcn_mfma_f32_16x16x32_bf16(a1, b, acc1[cf], 0, 0, 0);
            }
        }
    }

    // store partials: Pp[h][row 0..16383][col 0..127]
    // C layout: col = l15 (+cf*16), row = lg*4 + q (+16 for acc1)
    float* pb = Pp + ((size_t)h * NROWS + rowbase + w * 32) * 128;
#pragma unroll
    for (int cf = 0; cf < 8; ++cf) {
#pragma unroll
        for (int q = 0; q < 4; ++q) {
            int r0 = lg * 4 + q;
            int c  = cf * 16 + l15;
            pb[(r0     ) * 128 + c] = acc0[cf][q];
            pb[(r0 + 16) * 128 + c] = acc1[cf][q];
        }
    }
}

// ---------------- Stage 5: combine K-halves, ratio + mu + bias ------------
__global__ __launch_bounds__(256) void reduce_kernel(
    const float* __restrict__ Pp, const float* __restrict__ bias,
    const float* __restrict__ muptr, float* __restrict__ out)
{
    int idx = blockIdx.x * 256 + threadIdx.x;   // 1M outputs
    int r = idx >> 6, c = idx & 63;
    const size_t qs = (size_t)NROWS * 128;
    const float* p = Pp + (size_t)r * 128 + c;
    float T = p[0]  + p[qs];
    float D = p[64] + p[qs + 64];
    out[idx] = T / D + muptr[0] + bias[c];
}

extern "C" void kernel_launch(void* const* d_in, const int* in_sizes, int n_in,
                              void* d_out, int out_size, void* d_ws, size_t ws_size,
                              hipStream_t stream)
{
    const float* inp  = (const float*)d_in[0];
    const float* adj  = (const float*)d_in[1];
    const float* W    = (const float*)d_in[2];
    const float* bias = (const float*)d_in[3];
    const int*   p    = (const int*)d_in[4];
    float* out = (float*)d_out;

    // ws layout: Bt 4MB | partmin 1KB | mu | Wt 64KB | (8MB:) Pp 16MB
    char* ws = (char*)d_ws;
    u16*   Bt      = (u16*)ws;
    float* partmin = (float*)(ws + (size_t)4 * 1024 * 1024);
    float* mu      = partmin + 256;
    float* Wt      = (float*)(ws + (size_t)4 * 1024 * 1024 + 4096);
    float* Pp      = (float*)(ws + (size_t)8 * 1024 * 1024);

    float* sup = out;   // park support in d_out; reduce overwrites at the end

    wt_kernel       <<<64,   256, 0, stream>>>(W, Wt);
    support_kernel  <<<512,  256, 0, stream>>>(inp, Wt, sup);
    min_part_kernel <<<256,  256, 0, stream>>>(sup, partmin);
    min_final_kernel<<<1,    256, 0, stream>>>(partmin, mu);
    build_bt_kernel <<<64,   256, 0, stream>>>(sup, mu, p, Bt);
    gemm_kernel     <<<256,  256, 0, stream>>>(adj, Bt, Pp);
    reduce_kernel   <<<4096, 256, 0, stream>>>(Pp, bias, mu, out);
}

// Round 8
// 290.992 us; speedup vs baseline: 1.6435x; 1.5405x over previous
//
#include <hip/hip_runtime.h>
#include <hip/hip_bf16.h>

typedef __attribute__((ext_vector_type(8))) short short8;
typedef __attribute__((ext_vector_type(4))) float f32x4;
typedef unsigned short u16;
typedef unsigned int u32;

#define NROWS 16384
#define KDIM 16384
#define EPS 1e-6f

__device__ __forceinline__ u16 f2bf(float x) {
    union { float f; u32 u; } v; v.f = x;
    u32 u = v.u;
    u32 r = (u + 0x7FFFu + ((u >> 16) & 1u)) >> 16;  // RNE
    return (u16)r;
}

__device__ __forceinline__ void glds16(const void* g, void* l) {
    __builtin_amdgcn_global_load_lds(
        (const __attribute__((address_space(1))) void*)g,
        (__attribute__((address_space(3))) void*)l, 16, 0, 0);
}

__device__ __forceinline__ short cvbf(float x) {
    __hip_bfloat16 h = __float2bfloat16(x);
    return *(short*)&h;
}

// ---------------- Stage 0: transpose weight -> Wt[64][256] ----------------
__global__ __launch_bounds__(256) void wt_kernel(const float* __restrict__ W,
                                                 float* __restrict__ Wt) {
    int idx = blockIdx.x * 256 + threadIdx.x;  // 16384
    int k = idx >> 6, c = idx & 63;
    Wt[c * 256 + k] = W[idx];
}

// ---------------- Stage 1: support = input @ W (fp32) ---------------------
__global__ __launch_bounds__(256) void support_kernel(
    const float* __restrict__ inp, const float* __restrict__ Wt,
    float* __restrict__ sup)
{
    int tid = threadIdx.x;
    int col = tid & 63;
    int rr = tid >> 6;                        // 0..3
    int rowbase = blockIdx.x * 32 + rr * 8;   // 8 rows per thread
    const float4* wt4 = (const float4*)(Wt + (size_t)col * 256);
    float acc[8];
#pragma unroll
    for (int i = 0; i < 8; ++i) acc[i] = 0.f;
    for (int k4 = 0; k4 < 64; ++k4) {
        float4 wv = wt4[k4];
#pragma unroll
        for (int i = 0; i < 8; ++i) {
            float4 iv = *((const float4*)(inp + (size_t)(rowbase + i) * 256) + k4);
            acc[i] += iv.x * wv.x + iv.y * wv.y + iv.z * wv.z + iv.w * wv.w;
        }
    }
#pragma unroll
    for (int i = 0; i < 8; ++i)
        sup[(size_t)(rowbase + i) * 64 + col] = acc[i];
}

// ---------------- Stage 2: global min ------------------------------------
__global__ __launch_bounds__(256) void min_part_kernel(
    const float* __restrict__ sup, float* __restrict__ partmin)
{
    __shared__ float wmin[4];
    int tid = threadIdx.x;
    const float4* s4 = (const float4*)sup;
    size_t idx = (size_t)blockIdx.x * 256 + tid;
    float m = 3.4e38f;
#pragma unroll
    for (int j = 0; j < 4; ++j) {
        float4 v = s4[idx + (size_t)j * 65536];
        m = fminf(m, fminf(fminf(v.x, v.y), fminf(v.z, v.w)));
    }
#pragma unroll
    for (int off = 32; off; off >>= 1) m = fminf(m, __shfl_down(m, off, 64));
    if ((tid & 63) == 0) wmin[tid >> 6] = m;
    __syncthreads();
    if (tid == 0)
        partmin[blockIdx.x] = fminf(fminf(wmin[0], wmin[1]), fminf(wmin[2], wmin[3]));
}

__global__ __launch_bounds__(256) void min_final_kernel(
    const float* __restrict__ partmin, float* __restrict__ mu)
{
    __shared__ float wmin[4];
    int tid = threadIdx.x;
    float m = partmin[tid];
#pragma unroll
    for (int off = 32; off; off >>= 1) m = fminf(m, __shfl_down(m, off, 64));
    if ((tid & 63) == 0) wmin[tid >> 6] = m;
    __syncthreads();
    if (tid == 0)
        mu[0] = fminf(fminf(wmin[0], wmin[1]), fminf(wmin[2], wmin[3]));
}

// ---------------- Stage 3: Bt[n][k] bf16; n<64: s^(p+1), n>=64: s^p -------
__global__ __launch_bounds__(256) void build_bt_kernel(
    const float* __restrict__ sup, const float* __restrict__ muptr,
    const int* __restrict__ pptr, u16* __restrict__ Bt)
{
    int k = blockIdx.x * 256 + threadIdx.x;   // 0..16383
    float mu = *muptr;
    int p = *pptr;
    const float4* srow = (const float4*)(sup + (size_t)k * 64);
#pragma unroll
    for (int j = 0; j < 16; ++j) {
        float4 v = srow[j];
        float ss[4] = {v.x, v.y, v.z, v.w};
#pragma unroll
        for (int q = 0; q < 4; ++q) {
            int c = j * 4 + q;
            float s = ss[q] - mu + EPS;
            float d = 1.f;
            for (int i = 0; i < p; ++i) d *= s;   // s^p
            Bt[(size_t)c * KDIM + k] = f2bf(d * s);          // top
            Bt[(size_t)(c + 64) * KDIM + k] = f2bf(d);       // down
        }
    }
}

// ---------------- Stage 4: GEMM partials, K-split=2 -----------------------
// R2 skeleton (BM=64, BN=128, BK=64, 512 thr, grid 512 = 2 blocks/CU,
// depth-1 B via glds, plain __syncthreads) with two LDS-traffic cuts:
//  (1) A stored bf16 (8 KB/tile) via reg-staging with a DEPTH-2 A-register
//      pipeline: loadA(t+2) issues at top of iter t; writeA(t+1) consumes
//      registers loaded a full iteration earlier (no latency on barrier path).
//  (2) wave grid 2M x 4N: per-block-iter LDS = 88 KB vs R2's 128 KB (-31%).
// LDS 48 KB/block -> 2 blocks/CU. Natural h=blockIdx&1 pins each XCD to one
// 2MB Bt half (L2-resident).
#define BM 64
#define BN 128
#define BK 64
#define KH 8192
#define NTI 128   // KH/BK

__global__ __launch_bounds__(512, 4) void gemm_kernel(
    const float* __restrict__ adj, const u16* __restrict__ Bt,
    float* __restrict__ Pp)
{
    __shared__ __align__(16) u16 Ash[2][BM * BK];   //  8 KB x2 (bf16)
    __shared__ __align__(16) u16 Bsh[2][BN * BK];   // 16 KB x2 (bf16)

    const int tid = threadIdx.x;
    const int rb = blockIdx.x >> 1;
    const int h  = blockIdx.x & 1;
    const size_t rowbase = (size_t)rb * BM;
    const size_t kbase   = (size_t)h * KH;

    // --- A staging: 512 granules (16 B bf16 = 8 floats), 8 granules/row.
    // thread t loads global chunk c=t&7 of row r=t>>3 (32 B contiguous),
    // writes LDS slot c^(r&7)  => LDS[r][s] holds global chunk s^(r&7).
    const int ar = tid >> 3, ac = tid & 7;
    const float* asrc = adj + (rowbase + ar) * KDIM + kbase + ac * 8;
    const int awslot = ar * 8 + (ac ^ (ar & 7));

    // --- B staging (glds, linear dest + inverse-swizzled source), as R2
    const int ga0 = tid, ga1 = tid + 512;
    const int bn0 = ga0 >> 3, bx0 = (ga0 & 7) ^ (bn0 & 7);
    const int bn1 = ga1 >> 3, bx1 = (ga1 & 7) ^ (bn1 & 7);
    const u16* bsrc0 = Bt + (size_t)bn0 * KDIM + kbase + bx0 * 8;
    const u16* bsrc1 = Bt + (size_t)bn1 * KDIM + kbase + bx1 * 8;

    // --- compute indices: 8 waves = 2M x 4N
    const int lane = tid & 63;
    const int w    = tid >> 6;
    const int wm   = w >> 2;                // 0..1 : 32-row half
    const int wn   = w & 3;                 // 0..3 : 16-col group
    const int l15  = lane & 15, lg = lane >> 4;
    const int arow0 = wm * 32 + l15;
    const int arow1 = arow0 + 16;
    const int asw   = arow0 & 7;            // == arow1 & 7
    const int n0    = wn * 16 + l15;        // top col; down = n0+64
    const int nd    = n0 + 64;
    const int bsw   = n0 & 7;               // == nd & 7

    f32x4 acc00 = {0.f, 0.f, 0.f, 0.f};
    f32x4 acc01 = acc00, acc10 = acc00, acc11 = acc00;

    auto gldsB = [&](int kt, int buf) {
        char* bb = (char*)Bsh[buf];
        const int koff = kt * BK;
        glds16(bsrc0 + koff, bb + ga0 * 16);
        glds16(bsrc1 + koff, bb + ga1 * 16);
    };
    auto loadA = [&](int kt, float4& x, float4& y) {
        const float4* p = (const float4*)(asrc + kt * BK);
        x = p[0]; y = p[1];
    };
    auto writeA = [&](const float4& x, const float4& y, int buf) {
        uint4 v;
        v.x = (u32)(u16)cvbf(x.x) | ((u32)(u16)cvbf(x.y) << 16);
        v.y = (u32)(u16)cvbf(x.z) | ((u32)(u16)cvbf(x.w) << 16);
        v.z = (u32)(u16)cvbf(y.x) | ((u32)(u16)cvbf(y.y) << 16);
        v.w = (u32)(u16)cvbf(y.z) | ((u32)(u16)cvbf(y.w) << 16);
        ((uint4*)Ash[buf])[awslot] = v;
    };
    auto compute = [&](int buf) {
        const short8* As8 = (const short8*)Ash[buf];
        const short8* Bs8 = (const short8*)Bsh[buf];
#pragma unroll
        for (int ks = 0; ks < 2; ++ks) {
            const int g = ks * 4 + lg;
            short8 a0 = As8[arow0 * 8 + (g ^ asw)];
            short8 a1 = As8[arow1 * 8 + (g ^ asw)];
            short8 bt_ = Bs8[n0 * 8 + (g ^ bsw)];
            short8 bd_ = Bs8[nd * 8 + (g ^ bsw)];
            acc00 = __builtin_amdgcn_mfma_f32_16x16x32_bf16(a0, bt_, acc00, 0, 0, 0);
            acc01 = __builtin_amdgcn_mfma_f32_16x16x32_bf16(a0, bd_, acc01, 0, 0, 0);
            acc10 = __builtin_amdgcn_mfma_f32_16x16x32_bf16(a1, bt_, acc10, 0, 0, 0);
            acc11 = __builtin_amdgcn_mfma_f32_16x16x32_bf16(a1, bd_, acc11, 0, 0, 0);
        }
    };

    float4 pa0, pa1;   // A-reg set holding tile t+1 (even iters)
    float4 pb0, pb1;   // A-reg set holding tile t+2 in flight

    // prologue
    loadA(0, pa0, pa1);
    gldsB(0, 0);
    writeA(pa0, pa1, 0);      // one-time ~900cy wait, acceptable
    loadA(1, pa0, pa1);       // set A := tile 1
    __syncthreads();          // tile 0 resident

    for (int tt = 0; tt < NTI; tt += 2) {
        // ---- even iter: compute tile tt from buf0; A-regs pa = tile tt+1
        if (tt + 1 < NTI) gldsB(tt + 1, 1);
        if (tt + 2 < NTI) loadA(tt + 2, pb0, pb1);   // issue early
        compute(0);
        if (tt + 1 < NTI) writeA(pa0, pa1, 1);       // regs a full iter old
        __syncthreads();
        // ---- odd iter: compute tile tt+1 from buf1; A-regs pb = tile tt+2
        if (tt + 2 < NTI) gldsB(tt + 2, 0);
        if (tt + 3 < NTI) loadA(tt + 3, pa0, pa1);
        compute(1);
        if (tt + 2 < NTI) writeA(pb0, pb1, 0);
        __syncthreads();
    }

    // partial store: [block][64 rows][128 cols]; C: col=l15 base, row=lg*4+q
    float* pb = Pp + (size_t)blockIdx.x * (BM * BN);
#pragma unroll
    for (int q = 0; q < 4; ++q) {
        int r0 = wm * 32 + lg * 4 + q;
        int r1 = r0 + 16;
        pb[r0 * BN + n0] = acc00[q];
        pb[r0 * BN + nd] = acc01[q];
        pb[r1 * BN + n0] = acc10[q];
        pb[r1 * BN + nd] = acc11[q];
    }
}

// ---------------- Stage 5: combine K-halves, ratio + mu + bias ------------
__global__ __launch_bounds__(256) void reduce_kernel(
    const float* __restrict__ Pp, const float* __restrict__ bias,
    const float* __restrict__ muptr, float* __restrict__ out)
{
    int idx = blockIdx.x * 256 + threadIdx.x;   // 1M outputs
    int r = idx >> 6, c = idx & 63;
    int rb = r >> 6, rr = r & 63;
    const float* p0 = Pp + (size_t)(rb * 2) * (BM * BN) + rr * BN + c;
    const float* p1 = p0 + BM * BN;
    float T = p0[0]  + p1[0];
    float D = p0[64] + p1[64];
    out[idx] = T / D + muptr[0] + bias[c];
}

extern "C" void kernel_launch(void* const* d_in, const int* in_sizes, int n_in,
                              void* d_out, int out_size, void* d_ws, size_t ws_size,
                              hipStream_t stream)
{
    const float* inp  = (const float*)d_in[0];
    const float* adj  = (const float*)d_in[1];
    const float* W    = (const float*)d_in[2];
    const float* bias = (const float*)d_in[3];
    const int*   p    = (const int*)d_in[4];
    float* out = (float*)d_out;

    // ws layout: Bt 4MB | partmin 1KB | mu | Wt 64KB | (8MB:) Pp 16MB
    char* ws = (char*)d_ws;
    u16*   Bt      = (u16*)ws;
    float* partmin = (float*)(ws + (size_t)4 * 1024 * 1024);
    float* mu      = partmin + 256;
    float* Wt      = (float*)(ws + (size_t)4 * 1024 * 1024 + 4096);
    float* Pp      = (float*)(ws + (size_t)8 * 1024 * 1024);

    float* sup = out;   // park support in d_out; reduce overwrites at the end

    wt_kernel       <<<64,   256, 0, stream>>>(W, Wt);
    support_kernel  <<<512,  256, 0, stream>>>(inp, Wt, sup);
    min_part_kernel <<<256,  256, 0, stream>>>(sup, partmin);
    min_final_kernel<<<1,    256, 0, stream>>>(partmin, mu);
    build_bt_kernel <<<64,   256, 0, stream>>>(sup, mu, p, Bt);
    gemm_kernel     <<<512,  512, 0, stream>>>(adj, Bt, Pp);
    reduce_kernel   <<<4096, 256, 0, stream>>>(Pp, bias, mu, out);
}